// Round 1
// baseline (7063.058 us; speedup 1.0000x reference)
//
#include <hip/hip_runtime.h>
#include <cstdint>

// ---------------------------------------------------------------------------
// GCN twin-tower forward, f32 everywhere (round 1: correctness-first).
//
// Pipeline per tower t:
//   bn_stats -> bn_fold (fold BN into W1,b1) -> GEMM1(relu) -> GEMM2(relu)
//   -> deg count -> dinv -> edge norm
//   -> 3x { GEMM xw = h@Wc ; self-loop init ; edge scatter (f32 atomics) ;
//           bias+relu }
//   -> mean pool (atomics) -> write into concat buffer
// Head: GEMM(relu) x2 + final dot.
// ---------------------------------------------------------------------------

// ---------------- BN stats: per-feature sum / sumsq over N rows -------------
__global__ __launch_bounds__(256) void bn_stats_k(
    const float* __restrict__ x, float* __restrict__ bnsum,
    float* __restrict__ bnsq, int n) {
  __shared__ float ls[256], lq[256];
  const int tid = threadIdx.x;
  const int f = tid & 63;
  const int rb = tid >> 6;  // 0..3
  float s = 0.f, q = 0.f;
  for (int r = blockIdx.x * 4 + rb; r < n; r += gridDim.x * 4) {
    float v = x[(size_t)r * 64 + f];
    s += v;
    q += v * v;
  }
  ls[tid] = s;
  lq[tid] = q;
  __syncthreads();
  if (tid < 64) {
    s = ls[tid] + ls[tid + 64] + ls[tid + 128] + ls[tid + 192];
    q = lq[tid] + lq[tid + 64] + lq[tid + 128] + lq[tid + 192];
    atomicAdd(&bnsum[tid], s);
    atomicAdd(&bnsq[tid], q);
  }
}

// ------------- Fold BN affine into W1 (64x256) and b1 (256) ----------------
__global__ __launch_bounds__(256) void bn_fold_k(
    const float* __restrict__ bnsum, const float* __restrict__ bnsq,
    const float* __restrict__ gamma, const float* __restrict__ beta,
    const float* __restrict__ W1, const float* __restrict__ b1,
    float* __restrict__ W1f, float* __restrict__ b1f, float inv_n) {
  __shared__ float a[64], bf[64];
  const int tid = threadIdx.x;
  if (tid < 64) {
    float mu = bnsum[tid] * inv_n;
    float var = bnsq[tid] * inv_n - mu * mu;
    float s = gamma[tid] * rsqrtf(var + 1e-5f);
    a[tid] = s;
    bf[tid] = beta[tid] - mu * s;
  }
  __syncthreads();
  float acc = 0.f;
#pragma unroll
  for (int f = 0; f < 64; ++f) {
    float w = W1[f * 256 + tid];
    W1f[f * 256 + tid] = a[f] * w;
    acc += bf[f] * w;
  }
  b1f[tid] = b1[tid] + acc;
}

// ---------------- generic f32 tiled GEMM: C = relu?(A@B + bias) ------------
// A: [M,K] row-major, B: [K,N] row-major. Requires K%32==0, N%64==0.
__global__ __launch_bounds__(256) void gemm_f32(
    const float* __restrict__ A, const float* __restrict__ Bm,
    const float* __restrict__ bias, float* __restrict__ C, int M, int N, int K,
    int relu) {
  __shared__ float As[64][33];
  __shared__ float Bs[32][65];
  const int tid = threadIdx.x;
  const int bx = blockIdx.x, by = blockIdx.y;
  const int tc = tid & 15, tr = tid >> 4;
  const int row0 = by * 64 + tr * 4;
  const int col0 = bx * 64 + tc * 4;
  float acc[4][4] = {};
  for (int k0 = 0; k0 < K; k0 += 32) {
    {  // A tile 64x32
      const int idx = tid * 8;
      const int r = idx >> 5;
      const int c = idx & 31;
      const int grow = by * 64 + r;
      if (grow < M) {
        const float* s = A + (size_t)grow * K + k0 + c;
        float4 v0 = *(const float4*)s;
        float4 v1 = *(const float4*)(s + 4);
        As[r][c + 0] = v0.x; As[r][c + 1] = v0.y;
        As[r][c + 2] = v0.z; As[r][c + 3] = v0.w;
        As[r][c + 4] = v1.x; As[r][c + 5] = v1.y;
        As[r][c + 6] = v1.z; As[r][c + 7] = v1.w;
      } else {
#pragma unroll
        for (int j = 0; j < 8; ++j) As[r][c + j] = 0.f;
      }
    }
    {  // B tile 32x64
      const int idx = tid * 8;
      const int r = idx >> 6;
      const int c = idx & 63;
      const float* s = Bm + (size_t)(k0 + r) * N + bx * 64 + c;
      float4 v0 = *(const float4*)s;
      float4 v1 = *(const float4*)(s + 4);
      Bs[r][c + 0] = v0.x; Bs[r][c + 1] = v0.y;
      Bs[r][c + 2] = v0.z; Bs[r][c + 3] = v0.w;
      Bs[r][c + 4] = v1.x; Bs[r][c + 5] = v1.y;
      Bs[r][c + 6] = v1.z; Bs[r][c + 7] = v1.w;
    }
    __syncthreads();
#pragma unroll
    for (int k = 0; k < 32; ++k) {
      float a[4], b[4];
#pragma unroll
      for (int i = 0; i < 4; ++i) a[i] = As[tr * 4 + i][k];
#pragma unroll
      for (int j = 0; j < 4; ++j) b[j] = Bs[k][tc * 4 + j];
#pragma unroll
      for (int i = 0; i < 4; ++i)
#pragma unroll
        for (int j = 0; j < 4; ++j) acc[i][j] += a[i] * b[j];
    }
    __syncthreads();
  }
  float bv[4] = {0.f, 0.f, 0.f, 0.f};
  if (bias) {
#pragma unroll
    for (int j = 0; j < 4; ++j) bv[j] = bias[col0 + j];
  }
#pragma unroll
  for (int i = 0; i < 4; ++i) {
    int r = row0 + i;
    if (r < M) {
      float4 v;
      v.x = acc[i][0] + bv[0];
      v.y = acc[i][1] + bv[1];
      v.z = acc[i][2] + bv[2];
      v.w = acc[i][3] + bv[3];
      if (relu) {
        v.x = fmaxf(v.x, 0.f); v.y = fmaxf(v.y, 0.f);
        v.z = fmaxf(v.z, 0.f); v.w = fmaxf(v.w, 0.f);
      }
      *(float4*)(C + (size_t)r * N + col0) = v;
    }
  }
}

// ---------------- degree count (incoming edges per node) -------------------
__global__ __launch_bounds__(256) void count_deg_k(const int* __restrict__ dst,
                                                   int* __restrict__ cnt,
                                                   int e) {
  int i = blockIdx.x * 256 + threadIdx.x;
  if (i < e) atomicAdd(&cnt[dst[i]], 1);
}

__global__ __launch_bounds__(256) void dinv_k(const int* __restrict__ cnt,
                                              float* __restrict__ dinv, int n) {
  int i = blockIdx.x * 256 + threadIdx.x;
  if (i < n) dinv[i] = rsqrtf((float)(cnt[i] + 1));  // +1 self loop
}

__global__ __launch_bounds__(256) void norm_k(const int* __restrict__ src,
                                              const int* __restrict__ dst,
                                              const float* __restrict__ dinv,
                                              float* __restrict__ nrm, int e) {
  int i = blockIdx.x * 256 + threadIdx.x;
  if (i < e) nrm[i] = dinv[src[i]] * dinv[dst[i]];
}

// out[i,:] = xw[i,:]*dinv[i]^2   (self loop term), thread per float4
__global__ __launch_bounds__(256) void self_init_k(
    const float* __restrict__ xw, const float* __restrict__ dinv,
    float* __restrict__ out, int n) {
  int i = blockIdx.x * 256 + threadIdx.x;
  if (i >= n * 32) return;
  int node = i >> 5;
  float d = dinv[node];
  d = d * d;
  float4 v = ((const float4*)xw)[i];
  v.x *= d; v.y *= d; v.z *= d; v.w *= d;
  ((float4*)out)[i] = v;
}

// scatter: out[dst] += xw[src] * nrm, 32 threads (float4 each) per edge
__global__ __launch_bounds__(256) void scatter_k(
    const int* __restrict__ src, const int* __restrict__ dst,
    const float* __restrict__ nrm, const float* __restrict__ xw,
    float* __restrict__ out, int e) {
  int gid = blockIdx.x * 256 + threadIdx.x;
  int eid = gid >> 5;
  if (eid >= e) return;
  int q = gid & 31;
  int s = src[eid], d = dst[eid];
  float w = nrm[eid];
  float4 v = ((const float4*)(xw + (size_t)s * 128))[q];
  float* o = out + (size_t)d * 128 + q * 4;
  atomicAdd(o + 0, v.x * w);
  atomicAdd(o + 1, v.y * w);
  atomicAdd(o + 2, v.z * w);
  atomicAdd(o + 3, v.w * w);
}

__global__ __launch_bounds__(256) void bias_relu_k(float* __restrict__ h,
                                                   const float* __restrict__ b,
                                                   int n) {
  int i = blockIdx.x * 256 + threadIdx.x;
  if (i >= n * 32) return;
  int q = i & 31;
  float4 v = ((float4*)h)[i];
  float4 bb = ((const float4*)b)[q];
  v.x = fmaxf(v.x + bb.x, 0.f);
  v.y = fmaxf(v.y + bb.y, 0.f);
  v.z = fmaxf(v.z + bb.z, 0.f);
  v.w = fmaxf(v.w + bb.w, 0.f);
  ((float4*)h)[i] = v;
}

// ---------------- mean pool -------------------------------------------------
__global__ __launch_bounds__(256) void pool_cnt_k(const int* __restrict__ batch,
                                                  int* __restrict__ cnt,
                                                  int n) {
  int i = blockIdx.x * 256 + threadIdx.x;
  if (i < n) atomicAdd(&cnt[batch[i]], 1);
}

__global__ __launch_bounds__(256) void pool_sum_k(
    const float* __restrict__ h, const int* __restrict__ batch,
    float* __restrict__ psum, int n) {
  int i = blockIdx.x * 256 + threadIdx.x;
  if (i >= n * 32) return;
  int node = i >> 5, q = i & 31;
  int b = batch[node];
  float4 v = ((const float4*)h)[i];
  float* o = psum + (size_t)b * 128 + q * 4;
  atomicAdd(o + 0, v.x);
  atomicAdd(o + 1, v.y);
  atomicAdd(o + 2, v.z);
  atomicAdd(o + 3, v.w);
}

__global__ __launch_bounds__(256) void pool_div_k(
    const float* __restrict__ psum, const int* __restrict__ cnt,
    float* __restrict__ cat, int toff, int bn) {
  int i = blockIdx.x * 256 + threadIdx.x;
  if (i >= bn * 128) return;
  int b = i >> 7, f = i & 127;
  float c = fmaxf((float)cnt[b], 1.f);
  cat[(size_t)b * 256 + toff + f] = psum[i] / c;
}

// ---------------- final: out[r] = z2[r,:]@W5 + b5 --------------------------
__global__ __launch_bounds__(256) void final_k(const float* __restrict__ z2,
                                               const float* __restrict__ W5,
                                               const float* __restrict__ b5,
                                               float* __restrict__ out,
                                               int rows) {
  int r = blockIdx.x * 256 + threadIdx.x;
  if (r >= rows) return;
  float acc = b5[0];
#pragma unroll
  for (int k = 0; k < 128; ++k) acc += z2[(size_t)r * 128 + k] * W5[k];
  out[r] = acc;
}

// ---------------------------------------------------------------------------
extern "C" void kernel_launch(void* const* d_in, const int* in_sizes, int n_in,
                              void* d_out, int out_size, void* d_ws,
                              size_t ws_size, hipStream_t stream) {
  const float* x[2] = {(const float*)d_in[0], (const float*)d_in[3]};
  const int* ei[2] = {(const int*)d_in[1], (const int*)d_in[4]};
  const int* batch[2] = {(const int*)d_in[2], (const int*)d_in[5]};
  const float* gamma = (const float*)d_in[6];
  const float* beta = (const float*)d_in[7];
  const float* W1 = (const float*)d_in[8];
  const float* b1 = (const float*)d_in[9];
  const float* W2 = (const float*)d_in[10];
  const float* b2 = (const float*)d_in[11];
  const float* Wc[3] = {(const float*)d_in[12], (const float*)d_in[14],
                        (const float*)d_in[16]};
  const float* bc[3] = {(const float*)d_in[13], (const float*)d_in[15],
                        (const float*)d_in[17]};
  const float* W3 = (const float*)d_in[18];
  const float* b3 = (const float*)d_in[19];
  const float* W4 = (const float*)d_in[20];
  const float* b4 = (const float*)d_in[21];
  const float* W5 = (const float*)d_in[22];
  const float* b5 = (const float*)d_in[23];
  float* out = (float*)d_out;

  const int N = in_sizes[0] / 64;  // 50000
  const int E = in_sizes[1] / 2;   // 600000
  const int B = out_size;          // 512

  // ---- workspace layout (floats) ----
  float* ws = (float*)d_ws;
  float* bufA = ws;                           // N*256
  float* bufB = bufA + (size_t)N * 256;       // N*128
  float* bufC = bufB + (size_t)N * 128;       // N*128
  float* nrm = bufC + (size_t)N * 128;        // E
  float* dinv = nrm + E;                      // N
  int* degc = (int*)(dinv + N);               // N ints
  float* bnsum = (float*)(degc + N);          // 64
  float* bnsq = bnsum + 64;                   // 64
  float* W1f = bnsq + 64;                     // 16384
  float* b1f = W1f + 16384;                   // 256
  float* catb = b1f + 256;                    // B*256
  float* z1 = catb + (size_t)B * 256;         // B*256
  float* z2 = z1 + (size_t)B * 256;           // B*128
  float* psum = z2 + (size_t)B * 128;         // B*128
  int* pcnt = (int*)(psum + (size_t)B * 128); // B ints
  size_t need = (size_t)(pcnt + B) - (size_t)d_ws;
  if (ws_size < need) return;  // workspace too small -> fail loudly

  const int nb_e = (E + 255) / 256;
  const int nb_n = (N + 255) / 256;
  const int nb_nf = (N * 32 + 255) / 256;
  const int nb_sc = (E * 32 + 255) / 256;

  for (int t = 0; t < 2; ++t) {
    const int* srcp = ei[t];
    const int* dstp = ei[t] + E;

    hipMemsetAsync(bnsum, 0, 128 * sizeof(float), stream);
    hipMemsetAsync(degc, 0, (size_t)N * sizeof(int), stream);
    hipMemsetAsync(psum, 0, (size_t)B * 128 * sizeof(float) + B * sizeof(int),
                   stream);

    bn_stats_k<<<256, 256, 0, stream>>>(x[t], bnsum, bnsq, N);
    bn_fold_k<<<1, 256, 0, stream>>>(bnsum, bnsq, gamma, beta, W1, b1, W1f,
                                     b1f, 1.0f / (float)N);

    dim3 g1(4, (N + 63) / 64);
    gemm_f32<<<g1, 256, 0, stream>>>(x[t], W1f, b1f, bufA, N, 256, 64, 1);
    dim3 g2(2, (N + 63) / 64);
    gemm_f32<<<g2, 256, 0, stream>>>(bufA, W2, b2, bufB, N, 128, 256, 1);

    count_deg_k<<<nb_e, 256, 0, stream>>>(dstp, degc, E);
    dinv_k<<<nb_n, 256, 0, stream>>>(degc, dinv, N);
    norm_k<<<nb_e, 256, 0, stream>>>(srcp, dstp, dinv, nrm, E);

    float* hin = bufB;
    for (int c = 0; c < 3; ++c) {
      float* hout = (c == 1) ? bufB : bufA;  // ping-pong: B->A->B->A
      gemm_f32<<<g2, 256, 0, stream>>>(hin, Wc[c], nullptr, bufC, N, 128, 128,
                                       0);
      self_init_k<<<nb_nf, 256, 0, stream>>>(bufC, dinv, hout, N);
      scatter_k<<<nb_sc, 256, 0, stream>>>(srcp, dstp, nrm, bufC, hout, E);
      bias_relu_k<<<nb_nf, 256, 0, stream>>>(hout, bc[c], N);
      hin = hout;
    }

    pool_cnt_k<<<nb_n, 256, 0, stream>>>(batch[t], pcnt, N);
    pool_sum_k<<<nb_nf, 256, 0, stream>>>(hin, batch[t], psum, N);
    pool_div_k<<<(B * 128 + 255) / 256, 256, 0, stream>>>(psum, pcnt, catb,
                                                          t * 128, B);
  }

  dim3 gh1(4, (B + 63) / 64);
  gemm_f32<<<gh1, 256, 0, stream>>>(catb, W3, b3, z1, B, 256, 256, 1);
  dim3 gh2(2, (B + 63) / 64);
  gemm_f32<<<gh2, 256, 0, stream>>>(z1, W4, b4, z2, B, 128, 256, 1);
  final_k<<<(B + 255) / 256, 256, 0, stream>>>(z2, W5, b5, out, B);
}

// Round 2
// 1476.469 us; speedup vs baseline: 4.7838x; 4.7838x over previous
//
#include <hip/hip_runtime.h>
#include <cstdint>

// ---------------------------------------------------------------------------
// GCN twin-tower forward, f32. Round 2: replace atomic scatter with CSR gather.
//
// Per tower:
//   bn_stats -> bn_fold -> GEMM1(relu) -> GEMM2(relu)
//   -> deg count -> dinv -> edge norm
//   -> CSR build (scan + fill, dst-sorted edge list, reused by all 3 convs)
//   -> 3x { GEMM xw = h@Wc ; gather(self+edges+bias+relu) }
//   -> mean pool -> concat
// Head: GEMM(relu) x2 + final dot.
// ---------------------------------------------------------------------------

// ---------------- BN stats: per-feature sum / sumsq over N rows -------------
__global__ __launch_bounds__(256) void bn_stats_k(
    const float* __restrict__ x, float* __restrict__ bnsum,
    float* __restrict__ bnsq, int n) {
  __shared__ float ls[256], lq[256];
  const int tid = threadIdx.x;
  const int f = tid & 63;
  const int rb = tid >> 6;  // 0..3
  float s = 0.f, q = 0.f;
  for (int r = blockIdx.x * 4 + rb; r < n; r += gridDim.x * 4) {
    float v = x[(size_t)r * 64 + f];
    s += v;
    q += v * v;
  }
  ls[tid] = s;
  lq[tid] = q;
  __syncthreads();
  if (tid < 64) {
    s = ls[tid] + ls[tid + 64] + ls[tid + 128] + ls[tid + 192];
    q = lq[tid] + lq[tid + 64] + lq[tid + 128] + lq[tid + 192];
    atomicAdd(&bnsum[tid], s);
    atomicAdd(&bnsq[tid], q);
  }
}

// ------------- Fold BN affine into W1 (64x256) and b1 (256) ----------------
__global__ __launch_bounds__(256) void bn_fold_k(
    const float* __restrict__ bnsum, const float* __restrict__ bnsq,
    const float* __restrict__ gamma, const float* __restrict__ beta,
    const float* __restrict__ W1, const float* __restrict__ b1,
    float* __restrict__ W1f, float* __restrict__ b1f, float inv_n) {
  __shared__ float a[64], bf[64];
  const int tid = threadIdx.x;
  if (tid < 64) {
    float mu = bnsum[tid] * inv_n;
    float var = bnsq[tid] * inv_n - mu * mu;
    float s = gamma[tid] * rsqrtf(var + 1e-5f);
    a[tid] = s;
    bf[tid] = beta[tid] - mu * s;
  }
  __syncthreads();
  float acc = 0.f;
#pragma unroll
  for (int f = 0; f < 64; ++f) {
    float w = W1[f * 256 + tid];
    W1f[f * 256 + tid] = a[f] * w;
    acc += bf[f] * w;
  }
  b1f[tid] = b1[tid] + acc;
}

// ---------------- generic f32 tiled GEMM: C = relu?(A@B + bias) ------------
// A: [M,K] row-major, B: [K,N] row-major. Requires K%32==0, N%64==0.
__global__ __launch_bounds__(256) void gemm_f32(
    const float* __restrict__ A, const float* __restrict__ Bm,
    const float* __restrict__ bias, float* __restrict__ C, int M, int N, int K,
    int relu) {
  __shared__ float As[64][33];
  __shared__ float Bs[32][65];
  const int tid = threadIdx.x;
  const int bx = blockIdx.x, by = blockIdx.y;
  const int tc = tid & 15, tr = tid >> 4;
  const int row0 = by * 64 + tr * 4;
  const int col0 = bx * 64 + tc * 4;
  float acc[4][4] = {};
  for (int k0 = 0; k0 < K; k0 += 32) {
    {  // A tile 64x32
      const int idx = tid * 8;
      const int r = idx >> 5;
      const int c = idx & 31;
      const int grow = by * 64 + r;
      if (grow < M) {
        const float* s = A + (size_t)grow * K + k0 + c;
        float4 v0 = *(const float4*)s;
        float4 v1 = *(const float4*)(s + 4);
        As[r][c + 0] = v0.x; As[r][c + 1] = v0.y;
        As[r][c + 2] = v0.z; As[r][c + 3] = v0.w;
        As[r][c + 4] = v1.x; As[r][c + 5] = v1.y;
        As[r][c + 6] = v1.z; As[r][c + 7] = v1.w;
      } else {
#pragma unroll
        for (int j = 0; j < 8; ++j) As[r][c + j] = 0.f;
      }
    }
    {  // B tile 32x64
      const int idx = tid * 8;
      const int r = idx >> 6;
      const int c = idx & 63;
      const float* s = Bm + (size_t)(k0 + r) * N + bx * 64 + c;
      float4 v0 = *(const float4*)s;
      float4 v1 = *(const float4*)(s + 4);
      Bs[r][c + 0] = v0.x; Bs[r][c + 1] = v0.y;
      Bs[r][c + 2] = v0.z; Bs[r][c + 3] = v0.w;
      Bs[r][c + 4] = v1.x; Bs[r][c + 5] = v1.y;
      Bs[r][c + 6] = v1.z; Bs[r][c + 7] = v1.w;
    }
    __syncthreads();
#pragma unroll
    for (int k = 0; k < 32; ++k) {
      float a[4], b[4];
#pragma unroll
      for (int i = 0; i < 4; ++i) a[i] = As[tr * 4 + i][k];
#pragma unroll
      for (int j = 0; j < 4; ++j) b[j] = Bs[k][tc * 4 + j];
#pragma unroll
      for (int i = 0; i < 4; ++i)
#pragma unroll
        for (int j = 0; j < 4; ++j) acc[i][j] += a[i] * b[j];
    }
    __syncthreads();
  }
  float bv[4] = {0.f, 0.f, 0.f, 0.f};
  if (bias) {
#pragma unroll
    for (int j = 0; j < 4; ++j) bv[j] = bias[col0 + j];
  }
#pragma unroll
  for (int i = 0; i < 4; ++i) {
    int r = row0 + i;
    if (r < M) {
      float4 v;
      v.x = acc[i][0] + bv[0];
      v.y = acc[i][1] + bv[1];
      v.z = acc[i][2] + bv[2];
      v.w = acc[i][3] + bv[3];
      if (relu) {
        v.x = fmaxf(v.x, 0.f); v.y = fmaxf(v.y, 0.f);
        v.z = fmaxf(v.z, 0.f); v.w = fmaxf(v.w, 0.f);
      }
      *(float4*)(C + (size_t)r * N + col0) = v;
    }
  }
}

// ---------------- degree count (incoming edges per node) -------------------
__global__ __launch_bounds__(256) void count_deg_k(const int* __restrict__ dst,
                                                   int* __restrict__ cnt,
                                                   int e) {
  int i = blockIdx.x * 256 + threadIdx.x;
  if (i < e) atomicAdd(&cnt[dst[i]], 1);
}

__global__ __launch_bounds__(256) void dinv_k(const int* __restrict__ cnt,
                                              float* __restrict__ dinv, int n) {
  int i = blockIdx.x * 256 + threadIdx.x;
  if (i < n) dinv[i] = rsqrtf((float)(cnt[i] + 1));  // +1 self loop
}

__global__ __launch_bounds__(256) void norm_k(const int* __restrict__ src,
                                              const int* __restrict__ dst,
                                              const float* __restrict__ dinv,
                                              float* __restrict__ nrm, int e) {
  int i = blockIdx.x * 256 + threadIdx.x;
  if (i < e) nrm[i] = dinv[src[i]] * dinv[dst[i]];
}

// ---------------- CSR build: exclusive scan of deg over N ------------------
// scan1: per-block (1024 elems) sums
__global__ __launch_bounds__(256) void scan1_k(const int* __restrict__ deg,
                                               int* __restrict__ bsum, int n) {
  __shared__ int ls[256];
  const int base = blockIdx.x * 1024;
  int s = 0;
  for (int j = threadIdx.x; j < 1024; j += 256) {
    int i = base + j;
    s += (i < n) ? deg[i] : 0;
  }
  ls[threadIdx.x] = s;
  __syncthreads();
  for (int off = 128; off > 0; off >>= 1) {
    if (threadIdx.x < off) ls[threadIdx.x] += ls[threadIdx.x + off];
    __syncthreads();
  }
  if (threadIdx.x == 0) bsum[blockIdx.x] = ls[0];
}

// scan2: serial exclusive scan of block sums (nb ~ 49)
__global__ void scan2_k(int* __restrict__ bsum, int nb) {
  if (threadIdx.x == 0 && blockIdx.x == 0) {
    int acc = 0;
    for (int i = 0; i < nb; ++i) {
      int v = bsum[i];
      bsum[i] = acc;
      acc += v;
    }
  }
}

// scan3: write rowstart + cursor
__global__ __launch_bounds__(256) void scan3_k(
    const int* __restrict__ deg, const int* __restrict__ bsum,
    int* __restrict__ rowstart, int* __restrict__ cursor, int n, int e) {
  __shared__ int ts[256];
  const int tid = threadIdx.x;
  const int i0 = blockIdx.x * 1024 + tid * 4;
  int v[4];
  int s = 0;
#pragma unroll
  for (int j = 0; j < 4; ++j) {
    int i = i0 + j;
    v[j] = (i < n) ? deg[i] : 0;
    s += v[j];
  }
  ts[tid] = s;
  __syncthreads();
  for (int off = 1; off < 256; off <<= 1) {
    int t = (tid >= off) ? ts[tid - off] : 0;
    __syncthreads();
    ts[tid] += t;
    __syncthreads();
  }
  int run = bsum[blockIdx.x] + ts[tid] - s;  // exclusive prefix
#pragma unroll
  for (int j = 0; j < 4; ++j) {
    int i = i0 + j;
    if (i < n) {
      rowstart[i] = run;
      cursor[i] = run;
    }
    run += v[j];
  }
  if (blockIdx.x == 0 && tid == 0) rowstart[n] = e;
}

// fill: dst-sorted src + norm arrays
__global__ __launch_bounds__(256) void fill_k(
    const int* __restrict__ src, const int* __restrict__ dst,
    const float* __restrict__ nrm, int* __restrict__ cursor,
    int* __restrict__ esrc_s, float* __restrict__ enrm_s, int e) {
  int i = blockIdx.x * 256 + threadIdx.x;
  if (i >= e) return;
  int d = dst[i];
  int pos = atomicAdd(&cursor[d], 1);
  esrc_s[pos] = src[i];
  enrm_s[pos] = nrm[i];
}

// ---------------- gather: out[v] = relu(self + sum_in + bias) --------------
// 64 threads per node, float2 per thread (128 feat).
__global__ __launch_bounds__(256) void gather_k(
    const int* __restrict__ rowstart, const int* __restrict__ esrc_s,
    const float* __restrict__ enrm_s, const float* __restrict__ xw,
    const float* __restrict__ dinv, const float* __restrict__ bias,
    float* __restrict__ out, int n) {
  int gid = blockIdx.x * 256 + threadIdx.x;
  int v = gid >> 6;
  if (v >= n) return;
  int q = gid & 63;
  const float2* xw2 = (const float2*)xw;
  float d = dinv[v];
  float sl = d * d;
  float2 acc = xw2[(size_t)v * 64 + q];
  acc.x *= sl;
  acc.y *= sl;
  int s0 = rowstart[v], s1 = rowstart[v + 1];
  for (int e = s0; e < s1; ++e) {
    int s = esrc_s[e];
    float w = enrm_s[e];
    float2 t = xw2[(size_t)s * 64 + q];
    acc.x += t.x * w;
    acc.y += t.y * w;
  }
  float2 bb = ((const float2*)bias)[q];
  acc.x = fmaxf(acc.x + bb.x, 0.f);
  acc.y = fmaxf(acc.y + bb.y, 0.f);
  ((float2*)out)[(size_t)v * 64 + q] = acc;
}

// ---------------- mean pool -------------------------------------------------
__global__ __launch_bounds__(256) void pool_cnt_k(const int* __restrict__ batch,
                                                  int* __restrict__ cnt,
                                                  int n) {
  int i = blockIdx.x * 256 + threadIdx.x;
  if (i < n) atomicAdd(&cnt[batch[i]], 1);
}

__global__ __launch_bounds__(256) void pool_sum_k(
    const float* __restrict__ h, const int* __restrict__ batch,
    float* __restrict__ psum, int n) {
  int i = blockIdx.x * 256 + threadIdx.x;
  if (i >= n * 32) return;
  int node = i >> 5, q = i & 31;
  int b = batch[node];
  float4 v = ((const float4*)h)[i];
  float* o = psum + (size_t)b * 128 + q * 4;
  atomicAdd(o + 0, v.x);
  atomicAdd(o + 1, v.y);
  atomicAdd(o + 2, v.z);
  atomicAdd(o + 3, v.w);
}

__global__ __launch_bounds__(256) void pool_div_k(
    const float* __restrict__ psum, const int* __restrict__ cnt,
    float* __restrict__ cat, int toff, int bn) {
  int i = blockIdx.x * 256 + threadIdx.x;
  if (i >= bn * 128) return;
  int b = i >> 7, f = i & 127;
  float c = fmaxf((float)cnt[b], 1.f);
  cat[(size_t)b * 256 + toff + f] = psum[i] / c;
}

// ---------------- final: out[r] = z2[r,:]@W5 + b5 --------------------------
__global__ __launch_bounds__(256) void final_k(const float* __restrict__ z2,
                                               const float* __restrict__ W5,
                                               const float* __restrict__ b5,
                                               float* __restrict__ out,
                                               int rows) {
  int r = blockIdx.x * 256 + threadIdx.x;
  if (r >= rows) return;
  float acc = b5[0];
#pragma unroll
  for (int k = 0; k < 128; ++k) acc += z2[(size_t)r * 128 + k] * W5[k];
  out[r] = acc;
}

// ---------------------------------------------------------------------------
extern "C" void kernel_launch(void* const* d_in, const int* in_sizes, int n_in,
                              void* d_out, int out_size, void* d_ws,
                              size_t ws_size, hipStream_t stream) {
  const float* x[2] = {(const float*)d_in[0], (const float*)d_in[3]};
  const int* ei[2] = {(const int*)d_in[1], (const int*)d_in[4]};
  const int* batch[2] = {(const int*)d_in[2], (const int*)d_in[5]};
  const float* gamma = (const float*)d_in[6];
  const float* beta = (const float*)d_in[7];
  const float* W1 = (const float*)d_in[8];
  const float* b1 = (const float*)d_in[9];
  const float* W2 = (const float*)d_in[10];
  const float* b2 = (const float*)d_in[11];
  const float* Wc[3] = {(const float*)d_in[12], (const float*)d_in[14],
                        (const float*)d_in[16]};
  const float* bc[3] = {(const float*)d_in[13], (const float*)d_in[15],
                        (const float*)d_in[17]};
  const float* W3 = (const float*)d_in[18];
  const float* b3 = (const float*)d_in[19];
  const float* W4 = (const float*)d_in[20];
  const float* b4 = (const float*)d_in[21];
  const float* W5 = (const float*)d_in[22];
  const float* b5 = (const float*)d_in[23];
  float* out = (float*)d_out;

  const int N = in_sizes[0] / 64;  // 50000
  const int E = in_sizes[1] / 2;   // 600000
  const int B = out_size;          // 512

  // ---- workspace layout ----
  float* ws = (float*)d_ws;
  float* bufA = ws;                            // N*256
  float* bufB = bufA + (size_t)N * 256;        // N*128
  float* bufC = bufB + (size_t)N * 128;        // N*128
  float* nrm = bufC + (size_t)N * 128;         // E
  float* enrm_s = nrm + E;                     // E
  float* dinv = enrm_s + E;                    // N
  int* esrc_s = (int*)(dinv + N);              // E
  int* degc = esrc_s + E;                      // N
  int* rowstart = degc + N;                    // N+1
  int* cursor = rowstart + N + 1;              // N
  int* bsum = cursor + N;                      // 64
  float* bnsum = (float*)(bsum + 64);          // 64
  float* bnsq = bnsum + 64;                    // 64
  float* W1f = bnsq + 64;                      // 16384
  float* b1f = W1f + 16384;                    // 256
  float* catb = b1f + 256;                     // B*256
  float* z1 = catb + (size_t)B * 256;          // B*256
  float* z2 = z1 + (size_t)B * 256;            // B*128
  float* psum = z2 + (size_t)B * 128;          // B*128
  int* pcnt = (int*)(psum + (size_t)B * 128);  // B
  size_t need = (size_t)((char*)(pcnt + B) - (char*)d_ws);
  if (ws_size < need) return;  // workspace too small -> fail loudly

  const int nb_e = (E + 255) / 256;
  const int nb_n = (N + 255) / 256;
  const int nb_scan = (N + 1023) / 1024;
  const int nb_ga = (N * 64 + 255) / 256;
  const int nb_ps = (N * 32 + 255) / 256;

  for (int t = 0; t < 2; ++t) {
    const int* srcp = ei[t];
    const int* dstp = ei[t] + E;

    hipMemsetAsync(bnsum, 0, 128 * sizeof(float), stream);
    hipMemsetAsync(degc, 0, (size_t)N * sizeof(int), stream);
    hipMemsetAsync(psum, 0, (size_t)B * 128 * sizeof(float) + B * sizeof(int),
                   stream);

    bn_stats_k<<<256, 256, 0, stream>>>(x[t], bnsum, bnsq, N);
    bn_fold_k<<<1, 256, 0, stream>>>(bnsum, bnsq, gamma, beta, W1, b1, W1f,
                                     b1f, 1.0f / (float)N);

    dim3 g1(4, (N + 63) / 64);
    gemm_f32<<<g1, 256, 0, stream>>>(x[t], W1f, b1f, bufA, N, 256, 64, 1);
    dim3 g2(2, (N + 63) / 64);
    gemm_f32<<<g2, 256, 0, stream>>>(bufA, W2, b2, bufB, N, 128, 256, 1);

    count_deg_k<<<nb_e, 256, 0, stream>>>(dstp, degc, E);
    dinv_k<<<nb_n, 256, 0, stream>>>(degc, dinv, N);
    norm_k<<<nb_e, 256, 0, stream>>>(srcp, dstp, dinv, nrm, E);

    scan1_k<<<nb_scan, 256, 0, stream>>>(degc, bsum, N);
    scan2_k<<<1, 64, 0, stream>>>(bsum, nb_scan);
    scan3_k<<<nb_scan, 256, 0, stream>>>(degc, bsum, rowstart, cursor, N, E);
    fill_k<<<nb_e, 256, 0, stream>>>(srcp, dstp, nrm, cursor, esrc_s, enrm_s,
                                     E);

    float* hin = bufB;
    for (int c = 0; c < 3; ++c) {
      float* hout = (c == 1) ? bufB : bufA;  // ping-pong: B->A->B->A
      gemm_f32<<<g2, 256, 0, stream>>>(hin, Wc[c], nullptr, bufC, N, 128, 128,
                                       0);
      gather_k<<<nb_ga, 256, 0, stream>>>(rowstart, esrc_s, enrm_s, bufC, dinv,
                                          bc[c], hout, N);
      hin = hout;
    }

    pool_cnt_k<<<nb_n, 256, 0, stream>>>(batch[t], pcnt, N);
    pool_sum_k<<<nb_ps, 256, 0, stream>>>(hin, batch[t], psum, N);
    pool_div_k<<<(B * 128 + 255) / 256, 256, 0, stream>>>(psum, pcnt, catb,
                                                          t * 128, B);
  }

  dim3 gh1(4, (B + 63) / 64);
  gemm_f32<<<gh1, 256, 0, stream>>>(catb, W3, b3, z1, B, 256, 256, 1);
  dim3 gh2(2, (B + 63) / 64);
  gemm_f32<<<gh2, 256, 0, stream>>>(z1, W4, b4, z2, B, 128, 256, 1);
  final_k<<<(B + 255) / 256, 256, 0, stream>>>(z2, W5, b5, out, B);
}

// Round 3
// 1042.904 us; speedup vs baseline: 6.7725x; 1.4157x over previous
//
#include <hip/hip_runtime.h>
#include <cstdint>

// ---------------------------------------------------------------------------
// GCN twin-tower forward, f32. Round 3:
//   - pool via sorted-batch segmented reduction (no atomics)
//   - GEMM: 128x128 tile, 8x8/thread, transposed-A LDS, ds_read_b128 frags
//   - gather: 32 threads/node float4, packed (src,norm) int2 edges
// ---------------------------------------------------------------------------

// ---------------- BN stats: per-feature sum / sumsq over N rows -------------
__global__ __launch_bounds__(256) void bn_stats_k(
    const float* __restrict__ x, float* __restrict__ bnsum,
    float* __restrict__ bnsq, int n) {
  __shared__ float ls[256], lq[256];
  const int tid = threadIdx.x;
  const int f = tid & 63;
  const int rb = tid >> 6;  // 0..3
  float s = 0.f, q = 0.f;
  for (int r = blockIdx.x * 4 + rb; r < n; r += gridDim.x * 4) {
    float v = x[(size_t)r * 64 + f];
    s += v;
    q += v * v;
  }
  ls[tid] = s;
  lq[tid] = q;
  __syncthreads();
  if (tid < 64) {
    s = ls[tid] + ls[tid + 64] + ls[tid + 128] + ls[tid + 192];
    q = lq[tid] + lq[tid + 64] + lq[tid + 128] + lq[tid + 192];
    atomicAdd(&bnsum[tid], s);
    atomicAdd(&bnsq[tid], q);
  }
}

// ------------- Fold BN affine into W1 (64x256) and b1 (256) ----------------
__global__ __launch_bounds__(256) void bn_fold_k(
    const float* __restrict__ bnsum, const float* __restrict__ bnsq,
    const float* __restrict__ gamma, const float* __restrict__ beta,
    const float* __restrict__ W1, const float* __restrict__ b1,
    float* __restrict__ W1f, float* __restrict__ b1f, float inv_n) {
  __shared__ float a[64], bf[64];
  const int tid = threadIdx.x;
  if (tid < 64) {
    float mu = bnsum[tid] * inv_n;
    float var = bnsq[tid] * inv_n - mu * mu;
    float s = gamma[tid] * rsqrtf(var + 1e-5f);
    a[tid] = s;
    bf[tid] = beta[tid] - mu * s;
  }
  __syncthreads();
  float acc = 0.f;
#pragma unroll
  for (int f = 0; f < 64; ++f) {
    float w = W1[f * 256 + tid];
    W1f[f * 256 + tid] = a[f] * w;
    acc += bf[f] * w;
  }
  b1f[tid] = b1[tid] + acc;
}

// ---------------- f32 GEMM: C = relu?(A@B + bias) --------------------------
// A: [M,K] row-major, B: [K,N] row-major. Requires K%32==0, N%128==0.
// 128x128 tile, 256 threads, 8x8 per thread. A staged transposed in LDS.
__global__ __launch_bounds__(256) void gemm_f32(
    const float* __restrict__ A, const float* __restrict__ Bm,
    const float* __restrict__ bias, float* __restrict__ C, int M, int N, int K,
    int relu) {
  __shared__ float As[32][132];  // [k][m]  (transposed)
  __shared__ float Bs[32][132];  // [k][n]
  const int tid = threadIdx.x;
  const int bx = blockIdx.x, by = blockIdx.y;
  const int tn = tid & 15;   // col group (coalesced stores)
  const int tm = tid >> 4;   // row group
  const int row0 = by * 128 + tm * 8;
  const int col0 = bx * 128 + tn * 8;
  float acc[8][8] = {};
  for (int k0 = 0; k0 < K; k0 += 32) {
    // stage A tile 128(m) x 32(k), transposed into As[k][m]
#pragma unroll
    for (int p = 0; p < 4; ++p) {
      int flat = p * 1024 + tid * 4;
      int r = flat >> 5;   // 0..127  (m)
      int c = flat & 31;   // k, multiple of 4
      int grow = by * 128 + r;
      float4 v = make_float4(0.f, 0.f, 0.f, 0.f);
      if (grow < M) v = *(const float4*)(A + (size_t)grow * K + k0 + c);
      As[c + 0][r] = v.x;
      As[c + 1][r] = v.y;
      As[c + 2][r] = v.z;
      As[c + 3][r] = v.w;
    }
    // stage B tile 32(k) x 128(n)
#pragma unroll
    for (int p = 0; p < 4; ++p) {
      int flat = p * 1024 + tid * 4;
      int r = flat >> 7;    // 0..31 (k)
      int c = flat & 127;   // n, multiple of 4
      float4 v = *(const float4*)(Bm + (size_t)(k0 + r) * N + bx * 128 + c);
      *(float4*)&Bs[r][c] = v;
    }
    __syncthreads();
#pragma unroll
    for (int k = 0; k < 32; ++k) {
      float4 a0 = *(const float4*)&As[k][tm * 8];
      float4 a1 = *(const float4*)&As[k][tm * 8 + 4];
      float4 b0 = *(const float4*)&Bs[k][tn * 8];
      float4 b1 = *(const float4*)&Bs[k][tn * 8 + 4];
      float a[8] = {a0.x, a0.y, a0.z, a0.w, a1.x, a1.y, a1.z, a1.w};
      float b[8] = {b0.x, b0.y, b0.z, b0.w, b1.x, b1.y, b1.z, b1.w};
#pragma unroll
      for (int i = 0; i < 8; ++i)
#pragma unroll
        for (int j = 0; j < 8; ++j) acc[i][j] += a[i] * b[j];
    }
    __syncthreads();
  }
  float bv[8];
#pragma unroll
  for (int j = 0; j < 8; ++j) bv[j] = bias ? bias[col0 + j] : 0.f;
#pragma unroll
  for (int i = 0; i < 8; ++i) {
    int r = row0 + i;
    if (r >= M) continue;
    float4 v0, v1;
    v0.x = acc[i][0] + bv[0];
    v0.y = acc[i][1] + bv[1];
    v0.z = acc[i][2] + bv[2];
    v0.w = acc[i][3] + bv[3];
    v1.x = acc[i][4] + bv[4];
    v1.y = acc[i][5] + bv[5];
    v1.z = acc[i][6] + bv[6];
    v1.w = acc[i][7] + bv[7];
    if (relu) {
      v0.x = fmaxf(v0.x, 0.f); v0.y = fmaxf(v0.y, 0.f);
      v0.z = fmaxf(v0.z, 0.f); v0.w = fmaxf(v0.w, 0.f);
      v1.x = fmaxf(v1.x, 0.f); v1.y = fmaxf(v1.y, 0.f);
      v1.z = fmaxf(v1.z, 0.f); v1.w = fmaxf(v1.w, 0.f);
    }
    *(float4*)(C + (size_t)r * N + col0) = v0;
    *(float4*)(C + (size_t)r * N + col0 + 4) = v1;
  }
}

// ---------------- degree count (incoming edges per node) -------------------
__global__ __launch_bounds__(256) void count_deg_k(const int* __restrict__ dst,
                                                   int* __restrict__ cnt,
                                                   int e) {
  int i = blockIdx.x * 256 + threadIdx.x;
  if (i < e) atomicAdd(&cnt[dst[i]], 1);
}

__global__ __launch_bounds__(256) void dinv_k(const int* __restrict__ cnt,
                                              float* __restrict__ dinv, int n) {
  int i = blockIdx.x * 256 + threadIdx.x;
  if (i < n) dinv[i] = rsqrtf((float)(cnt[i] + 1));  // +1 self loop
}

// ---------------- CSR build: exclusive scan of deg over N ------------------
__global__ __launch_bounds__(256) void scan1_k(const int* __restrict__ deg,
                                               int* __restrict__ bsum, int n) {
  __shared__ int ls[256];
  const int base = blockIdx.x * 1024;
  int s = 0;
  for (int j = threadIdx.x; j < 1024; j += 256) {
    int i = base + j;
    s += (i < n) ? deg[i] : 0;
  }
  ls[threadIdx.x] = s;
  __syncthreads();
  for (int off = 128; off > 0; off >>= 1) {
    if (threadIdx.x < off) ls[threadIdx.x] += ls[threadIdx.x + off];
    __syncthreads();
  }
  if (threadIdx.x == 0) bsum[blockIdx.x] = ls[0];
}

__global__ void scan2_k(int* __restrict__ bsum, int nb) {
  if (threadIdx.x == 0 && blockIdx.x == 0) {
    int acc = 0;
    for (int i = 0; i < nb; ++i) {
      int v = bsum[i];
      bsum[i] = acc;
      acc += v;
    }
  }
}

__global__ __launch_bounds__(256) void scan3_k(
    const int* __restrict__ deg, const int* __restrict__ bsum,
    int* __restrict__ rowstart, int* __restrict__ cursor, int n, int e) {
  __shared__ int ts[256];
  const int tid = threadIdx.x;
  const int i0 = blockIdx.x * 1024 + tid * 4;
  int v[4];
  int s = 0;
#pragma unroll
  for (int j = 0; j < 4; ++j) {
    int i = i0 + j;
    v[j] = (i < n) ? deg[i] : 0;
    s += v[j];
  }
  ts[tid] = s;
  __syncthreads();
  for (int off = 1; off < 256; off <<= 1) {
    int t = (tid >= off) ? ts[tid - off] : 0;
    __syncthreads();
    ts[tid] += t;
    __syncthreads();
  }
  int run = bsum[blockIdx.x] + ts[tid] - s;  // exclusive prefix
#pragma unroll
  for (int j = 0; j < 4; ++j) {
    int i = i0 + j;
    if (i < n) {
      rowstart[i] = run;
      cursor[i] = run;
    }
    run += v[j];
  }
  if (blockIdx.x == 0 && tid == 0) rowstart[n] = e;
}

// fill: dst-sorted packed (src, norm) edges; norm computed inline
__global__ __launch_bounds__(256) void fillnorm_k(
    const int* __restrict__ src, const int* __restrict__ dst,
    const float* __restrict__ dinv, int* __restrict__ cursor,
    int2* __restrict__ epack, int e) {
  int i = blockIdx.x * 256 + threadIdx.x;
  if (i >= e) return;
  int s = src[i], d = dst[i];
  int pos = atomicAdd(&cursor[d], 1);
  epack[pos] = make_int2(s, __float_as_int(dinv[s] * dinv[d]));
}

// ---------------- gather: out[v] = relu(self + sum_in + bias) --------------
// 32 threads per node, float4 per thread (128 feat).
__global__ __launch_bounds__(256) void gather_k(
    const int* __restrict__ rowstart, const int2* __restrict__ epack,
    const float* __restrict__ xw, const float* __restrict__ dinv,
    const float* __restrict__ bias, float* __restrict__ out, int n) {
  int gid = blockIdx.x * 256 + threadIdx.x;
  int v = gid >> 5;
  if (v >= n) return;
  int q = gid & 31;
  const float4* xw4 = (const float4*)xw;
  float d = dinv[v];
  float sl = d * d;
  float4 acc = xw4[(size_t)v * 32 + q];
  acc.x *= sl; acc.y *= sl; acc.z *= sl; acc.w *= sl;
  int s0 = rowstart[v], s1 = rowstart[v + 1];
  for (int e = s0; e < s1; ++e) {
    int2 ed = epack[e];
    float w = __int_as_float(ed.y);
    float4 t = xw4[(size_t)ed.x * 32 + q];
    acc.x += t.x * w;
    acc.y += t.y * w;
    acc.z += t.z * w;
    acc.w += t.w * w;
  }
  float4 bb = ((const float4*)bias)[q];
  acc.x = fmaxf(acc.x + bb.x, 0.f);
  acc.y = fmaxf(acc.y + bb.y, 0.f);
  acc.z = fmaxf(acc.z + bb.z, 0.f);
  acc.w = fmaxf(acc.w + bb.w, 0.f);
  ((float4*)out)[(size_t)v * 32 + q] = acc;
}

// ---------------- pool: segmented mean over sorted batch -------------------
// bstart[b] = lower_bound(batch, b), b in [0, B]
__global__ __launch_bounds__(256) void bstart_k(const int* __restrict__ batch,
                                                int* __restrict__ bstart,
                                                int n, int nb) {
  int b = blockIdx.x * 256 + threadIdx.x;
  if (b > nb) return;
  int lo = 0, hi = n;
  while (lo < hi) {
    int mid = (lo + hi) >> 1;
    if (batch[mid] < b) lo = mid + 1; else hi = mid;
  }
  bstart[b] = lo;
}

// one block (128 threads) per graph; h rows are contiguous per graph
__global__ __launch_bounds__(128) void pool_seg_k(
    const float* __restrict__ h, const int* __restrict__ bstart,
    float* __restrict__ cat, int toff) {
  int b = blockIdx.x;
  int s = bstart[b], e = bstart[b + 1];
  int f = threadIdx.x;
  float acc = 0.f;
  for (int v = s; v < e; ++v) acc += h[(size_t)v * 128 + f];
  float c = fmaxf((float)(e - s), 1.f);
  cat[(size_t)b * 256 + toff + f] = acc / c;
}

// ---------------- final: out[r] = z2[r,:]@W5 + b5 --------------------------
__global__ __launch_bounds__(256) void final_k(const float* __restrict__ z2,
                                               const float* __restrict__ W5,
                                               const float* __restrict__ b5,
                                               float* __restrict__ out,
                                               int rows) {
  int r = blockIdx.x * 256 + threadIdx.x;
  if (r >= rows) return;
  float acc = b5[0];
#pragma unroll
  for (int k = 0; k < 128; ++k) acc += z2[(size_t)r * 128 + k] * W5[k];
  out[r] = acc;
}

// ---------------------------------------------------------------------------
extern "C" void kernel_launch(void* const* d_in, const int* in_sizes, int n_in,
                              void* d_out, int out_size, void* d_ws,
                              size_t ws_size, hipStream_t stream) {
  const float* x[2] = {(const float*)d_in[0], (const float*)d_in[3]};
  const int* ei[2] = {(const int*)d_in[1], (const int*)d_in[4]};
  const int* batch[2] = {(const int*)d_in[2], (const int*)d_in[5]};
  const float* gamma = (const float*)d_in[6];
  const float* beta = (const float*)d_in[7];
  const float* W1 = (const float*)d_in[8];
  const float* b1 = (const float*)d_in[9];
  const float* W2 = (const float*)d_in[10];
  const float* b2 = (const float*)d_in[11];
  const float* Wc[3] = {(const float*)d_in[12], (const float*)d_in[14],
                        (const float*)d_in[16]};
  const float* bc[3] = {(const float*)d_in[13], (const float*)d_in[15],
                        (const float*)d_in[17]};
  const float* W3 = (const float*)d_in[18];
  const float* b3 = (const float*)d_in[19];
  const float* W4 = (const float*)d_in[20];
  const float* b4 = (const float*)d_in[21];
  const float* W5 = (const float*)d_in[22];
  const float* b5 = (const float*)d_in[23];
  float* out = (float*)d_out;

  const int N = in_sizes[0] / 64;  // 50000
  const int E = in_sizes[1] / 2;   // 600000
  const int B = out_size;          // 512

  // ---- workspace layout ----
  float* ws = (float*)d_ws;
  float* bufA = ws;                            // N*256
  float* bufB = bufA + (size_t)N * 256;        // N*128
  float* bufC = bufB + (size_t)N * 128;        // N*128
  float* dinv = bufC + (size_t)N * 128;        // N
  int2* epack = (int2*)(dinv + N);             // E int2 (8B, offset even)
  int* degc = (int*)(epack + E);               // N
  int* rowstart = degc + N;                    // N+1
  int* cursor = rowstart + N + 1;              // N
  int* bsum = cursor + N;                      // 64
  int* bstart = bsum + 64;                     // B+1
  float* bnsum = (float*)(bstart + B + 1);     // 64
  float* bnsq = bnsum + 64;                    // 64
  float* W1f = bnsq + 64;                      // 16384
  float* b1f = W1f + 16384;                    // 256
  float* catb = b1f + 256;                     // B*256
  float* z1 = catb + (size_t)B * 256;          // B*256
  float* z2 = z1 + (size_t)B * 256;            // B*128
  size_t need = (size_t)((char*)(z2 + (size_t)B * 128) - (char*)d_ws);
  if (ws_size < need) return;  // workspace too small -> fail loudly

  const int nb_e = (E + 255) / 256;
  const int nb_n = (N + 255) / 256;
  const int nb_scan = (N + 1023) / 1024;
  const int nb_ga = (N * 32 + 255) / 256;

  for (int t = 0; t < 2; ++t) {
    const int* srcp = ei[t];
    const int* dstp = ei[t] + E;

    hipMemsetAsync(bnsum, 0, 128 * sizeof(float), stream);
    hipMemsetAsync(degc, 0, (size_t)N * sizeof(int), stream);

    bn_stats_k<<<256, 256, 0, stream>>>(x[t], bnsum, bnsq, N);
    bn_fold_k<<<1, 256, 0, stream>>>(bnsum, bnsq, gamma, beta, W1, b1, W1f,
                                     b1f, 1.0f / (float)N);

    dim3 g1(2, (N + 127) / 128);
    gemm_f32<<<g1, 256, 0, stream>>>(x[t], W1f, b1f, bufA, N, 256, 64, 1);
    dim3 g2(1, (N + 127) / 128);
    gemm_f32<<<g2, 256, 0, stream>>>(bufA, W2, b2, bufB, N, 128, 256, 1);

    count_deg_k<<<nb_e, 256, 0, stream>>>(dstp, degc, E);
    dinv_k<<<nb_n, 256, 0, stream>>>(degc, dinv, N);

    scan1_k<<<nb_scan, 256, 0, stream>>>(degc, bsum, N);
    scan2_k<<<1, 64, 0, stream>>>(bsum, nb_scan);
    scan3_k<<<nb_scan, 256, 0, stream>>>(degc, bsum, rowstart, cursor, N, E);
    fillnorm_k<<<nb_e, 256, 0, stream>>>(srcp, dstp, dinv, cursor, epack, E);

    bstart_k<<<(B + 256) / 256, 256, 0, stream>>>(batch[t], bstart, N, B);

    float* hin = bufB;
    for (int c = 0; c < 3; ++c) {
      float* hout = (c == 1) ? bufB : bufA;  // ping-pong: B->A->B->A
      gemm_f32<<<g2, 256, 0, stream>>>(hin, Wc[c], nullptr, bufC, N, 128, 128,
                                       0);
      gather_k<<<nb_ga, 256, 0, stream>>>(rowstart, epack, bufC, dinv, bc[c],
                                          hout, N);
      hin = hout;
    }

    pool_seg_k<<<B, 128, 0, stream>>>(hin, bstart, catb, t * 128);
  }

  dim3 gh1(2, (B + 127) / 128);
  gemm_f32<<<gh1, 256, 0, stream>>>(catb, W3, b3, z1, B, 256, 256, 1);
  dim3 gh2(1, (B + 127) / 128);
  gemm_f32<<<gh2, 256, 0, stream>>>(z1, W4, b4, z2, B, 128, 256, 1);
  final_k<<<(B + 255) / 256, 256, 0, stream>>>(z2, W5, b5, out, B);
}